// Round 3
// baseline (314.726 us; speedup 1.0000x reference)
//
#include <hip/hip_runtime.h>
#include <math.h>

// LSQ quantizer with Hadamard rotation via FWHT:
//   out_row = FWHT( h0 .* s .* rint(clamp(FWHT(x_row) .* h0 / s, -Qn, Qp)) )
// with h0 = hadamard[0,:] = signs/sqrt(D)  (H = H_sylvester*diag(signs)/sqrt(D),
// H_sylvester symmetric, row 0 of H_sylvester = all-ones).
//
// Round-3:
//  * Single conflict-free LDS map for all transposes. Element j with bit
//    fields a=j[2:5], b=j[5:8], c=j[8:11] lives at float4-cell
//        q = c*64 + b*8 + (a^b)
//    Every access pattern (A: reg=c, lane=(b,a); B: reg=a, lane=(c,b);
//    C: reg=b, lane=(c,a)) has bank-quad = a^b, a permutation within each
//    8-lane group -> zero conflicts (round-2's B<->C map serialized 8-way).
//  * Grid-stride, 4 rows/wave, next row's globals prefetched during current
//    row's compute (kernel was latency-bound: no pipe >42% busy).

constexpr int D  = 2048;
constexpr int NR = 8;   // float4 regs per lane: 8 * 4 * 64 = 2048

#define LGKM0() __asm__ __volatile__("s_waitcnt lgkmcnt(0)" ::: "memory")

__device__ __forceinline__ void bfly(float4& a, float4& b) {
    float4 ta = a, tb = b;
    a.x = ta.x + tb.x; a.y = ta.y + tb.y; a.z = ta.z + tb.z; a.w = ta.w + tb.w;
    b.x = ta.x - tb.x; b.y = ta.y - tb.y; b.z = ta.z - tb.z; b.w = ta.w - tb.w;
}

// butterflies over the 3 register-index bits (whatever j-bits they carry)
__device__ __forceinline__ void reg_stages(float4 (&v)[NR]) {
    #pragma unroll
    for (int m = 1; m <= 4; m <<= 1) {
        #pragma unroll
        for (int r = 0; r < NR; ++r)
            if ((r & m) == 0) bfly(v[r], v[r | m]);
    }
}

// butterflies over j bits {0,1} (float4 components)
__device__ __forceinline__ void comp_stages(float4 (&v)[NR]) {
    #pragma unroll
    for (int r = 0; r < NR; ++r) {
        float a, b;
        a = v[r].x; b = v[r].y; v[r].x = a + b; v[r].y = a - b;   // bit 0
        a = v[r].z; b = v[r].w; v[r].z = a + b; v[r].w = a - b;
        a = v[r].x; b = v[r].z; v[r].x = a + b; v[r].z = a - b;   // bit 1
        a = v[r].y; b = v[r].w; v[r].y = a + b; v[r].w = a - b;
    }
}

// hs = h0*s pre-folded; u = xh*hs/s^2 == xh*h0/s (up to 1-ulp scale rounding)
__device__ __forceinline__ float quant1(float xh, float hs, float inv_s2,
                                        float nqn, float qp) {
    float u = xh * hs * inv_s2;
    u = fminf(fmaxf(u, nqn), qp);             // clip(-Qn, Qp) -> v_med3
    return rintf(u) * hs;                     // round-half-even, *s, *h0
}

__global__ __launch_bounds__(256, 4) void lsq_fwht_kernel(
    const float* __restrict__ x,
    const float* __restrict__ scale,
    const float* __restrict__ hadamard,
    const int*   __restrict__ qn_p,
    const int*   __restrict__ qp_p,
    const int*   __restrict__ ne_p,
    float*       __restrict__ out,
    int rows, int stride)
{
    __shared__ float smem[4][D];              // 8 KiB per wave, wave-private

    const int lane = threadIdx.x & 63;
    const int wave = threadIdx.x >> 6;
    const int row0 = blockIdx.x * 4 + wave;
    if (row0 >= rows) return;                 // wave-uniform

    float* lds = smem[wave];
    const int llo = lane & 7;
    const int lhi = lane >> 3;

    // LSQ scale trick (forward value == scale), fp32 rounding as in reference
    const float sc    = scale[0];
    const float qp    = (float)qp_p[0];
    const float nqn   = -(float)qn_p[0];
    const float gs    = 1.0f / sqrtf((float)ne_p[0] * qp);
    const float bw    = sc * gs;
    const float s     = (sc - bw) + bw;
    const float inv_s = 1.0f / s;
    const float inv_s2 = inv_s * inv_s;

    // h0 in layout C (reg r carries b=j[5:8]; lane: llo=a, lhi=c), pre-*s
    float4 h[NR];
    {
        const float4* h4 = reinterpret_cast<const float4*>(hadamard);
        #pragma unroll
        for (int r = 0; r < NR; ++r) {
            h[r] = h4[lhi * 64 + r * 8 + llo];
            h[r].x *= s; h[r].y *= s; h[r].z *= s; h[r].w *= s;
        }
    }

    // LDS float-addresses into the unified map 4q, q = c*64 + b*8 + (a^b):
    //   A(r=c): r*256 + lhi*32 + ((llo^lhi)<<2)    lane: llo=a, lhi=b
    //   B(r=a): lhi*256 + llo*32 + ((r^llo)<<2)    lane: llo=b, lhi=c
    //   C(r=b): lhi*256 + r*32 + ((llo^r)<<2)      lane: llo=a, lhi=c
    const int aA  = lhi * 32 + ((llo ^ lhi) << 2);    // + r*256
    const int aBC = lhi * 256;                        // common base for B, C
    const int t2  = llo << 2;

    const float4* x4 = reinterpret_cast<const float4*>(x)   + lane;
    float4*       y4 = reinterpret_cast<float4*>(out)       + lane;

    // first row's loads
    float4 v[NR], p[NR];
    {
        const float4* src = x4 + (size_t)row0 * (D / 4);
        #pragma unroll
        for (int r = 0; r < NR; ++r) v[r] = src[(size_t)r * 64];
    }

    for (int row = row0; row < rows; row += stride) {
        const int nrow = row + stride;
        if (nrow < rows) {                    // prefetch next row (wave-uniform)
            const float4* src = x4 + (size_t)nrow * (D / 4);
            #pragma unroll
            for (int r = 0; r < NR; ++r) p[r] = src[(size_t)r * 64];
        }

        // ================= FWHT #1 =================
        comp_stages(v);                                   // bits 0,1
        reg_stages(v);                                    // bits 8,9,10 (c)
        #pragma unroll
        for (int r = 0; r < NR; ++r)                      // write A
            *reinterpret_cast<float4*>(lds + r * 256 + aA) = v[r];
        LGKM0();
        #pragma unroll
        for (int r = 0; r < NR; ++r)                      // read B
            v[r] = *reinterpret_cast<const float4*>(lds + aBC + llo * 32 + ((r << 2) ^ t2));
        reg_stages(v);                                    // bits 2,3,4 (a)
        #pragma unroll
        for (int r = 0; r < NR; ++r)                      // write B
            *reinterpret_cast<float4*>(lds + aBC + llo * 32 + ((r << 2) ^ t2)) = v[r];
        LGKM0();
        #pragma unroll
        for (int r = 0; r < NR; ++r)                      // read C
            v[r] = *reinterpret_cast<const float4*>(lds + aBC + r * 32 + ((r << 2) ^ t2));
        reg_stages(v);                                    // bits 5,6,7 (b)

        // ================= quantize (layout C) =================
        #pragma unroll
        for (int r = 0; r < NR; ++r) {
            v[r].x = quant1(v[r].x, h[r].x, inv_s2, nqn, qp);
            v[r].y = quant1(v[r].y, h[r].y, inv_s2, nqn, qp);
            v[r].z = quant1(v[r].z, h[r].z, inv_s2, nqn, qp);
            v[r].w = quant1(v[r].w, h[r].w, inv_s2, nqn, qp);
        }

        // ================= FWHT #2 =================
        reg_stages(v);                                    // bits 5,6,7 (b)
        #pragma unroll
        for (int r = 0; r < NR; ++r)                      // write C
            *reinterpret_cast<float4*>(lds + aBC + r * 32 + ((r << 2) ^ t2)) = v[r];
        LGKM0();
        #pragma unroll
        for (int r = 0; r < NR; ++r)                      // read B
            v[r] = *reinterpret_cast<const float4*>(lds + aBC + llo * 32 + ((r << 2) ^ t2));
        reg_stages(v);                                    // bits 2,3,4 (a)
        #pragma unroll
        for (int r = 0; r < NR; ++r)                      // write B
            *reinterpret_cast<float4*>(lds + aBC + llo * 32 + ((r << 2) ^ t2)) = v[r];
        LGKM0();
        #pragma unroll
        for (int r = 0; r < NR; ++r)                      // read A
            v[r] = *reinterpret_cast<const float4*>(lds + r * 256 + aA);
        reg_stages(v);                                    // bits 8,9,10 (c)
        comp_stages(v);                                   // bits 0,1

        // ---- store (layout A, coalesced) ----
        {
            float4* dst = y4 + (size_t)row * (D / 4);
            #pragma unroll
            for (int r = 0; r < NR; ++r) dst[(size_t)r * 64] = v[r];
        }

        if (nrow < rows) {
            #pragma unroll
            for (int r = 0; r < NR; ++r) v[r] = p[r];
        }
    }
}

extern "C" void kernel_launch(void* const* d_in, const int* in_sizes, int n_in,
                              void* d_out, int out_size, void* d_ws, size_t ws_size,
                              hipStream_t stream) {
    const float* x        = (const float*)d_in[0];
    const float* scale    = (const float*)d_in[1];
    const float* hadamard = (const float*)d_in[2];
    const int*   Qn       = (const int*)d_in[3];
    const int*   Qp       = (const int*)d_in[4];
    const int*   ne       = (const int*)d_in[5];
    float*       out      = (float*)d_out;

    const int rows = in_sizes[0] / D;          // 16384 for B=4,S=4096
    // 1024 blocks = 4 blocks/CU (16 waves/CU), uniform 4 rows per wave
    const int grid   = 1024;
    const int stride = grid * 4;

    lsq_fwht_kernel<<<grid, 256, 0, stream>>>(x, scale, hadamard, Qn, Qp, ne,
                                              out, rows, stride);
}